// Round 2
// baseline (548.107 us; speedup 1.0000x reference)
//
#include <hip/hip_runtime.h>
#include <math.h>

// Problem constants
#define K_    1024
#define N_    32768
#define NELEM 8388608

// d_out layout (floats, reference return order)
#define Q_OFF    1
#define PERP_OFF 8388609
#define IDX_OFF  8388610

typedef unsigned long long ull;
typedef _Float16 h8  __attribute__((ext_vector_type(8)));
typedef float    f4v __attribute__((ext_vector_type(4)));

// ws layout (bytes)
#define WS_COUNTS  0        // 1024 u32
#define WS_SUMSQ   4096     // double
#define WS_RISKCNT 4104     // u32
#define WS_EN2     4160     // 1024 f32
#define WS_XN2     8256     // 32768 f32
#define WS_IDX     139328   // 32768 i32
#define WS_RLIST   270400   // 32768 i32
#define WS_RKEY    401472   // 32768 u64
#define WS_EHI     663616   // 1024*256 fp16
#define WS_XHI     1187904  // 32768*256 fp16 (pixel-major)

// risky-gap threshold in the 1024-scaled domain.
// bound: 2*(2*2^-11*2.01*||x||*||e||)*1024 + 1024*(ref f32 rounding 6.2e-5) ~= 0.91
#define SWEEP_W 1.6f

// ---------------------------------------------------------------------------
// Convert codebook -> fp16 (scaled by 1024 to stay in normal range) + row norms
__global__ __launch_bounds__(256) void k_ecvt(const float* __restrict__ cb,
                                              ushort* __restrict__ ehi,
                                              float* __restrict__ en2) {
    __shared__ double esum[256];
    const int t = threadIdx.x;
    const int row = blockIdx.x * 64 + (t >> 2);
    const int seg = t & 3;
    const float* src = cb + (size_t)row * 256 + seg * 64;
    ushort* dst = ehi + (size_t)row * 256 + seg * 64;
    double s = 0.0;
#pragma unroll
    for (int i = 0; i < 8; ++i) {
        const float4 a = *(const float4*)(src + i * 8);
        const float4 b = *(const float4*)(src + i * 8 + 4);
        s += (double)a.x * a.x + (double)a.y * a.y + (double)a.z * a.z + (double)a.w * a.w;
        s += (double)b.x * b.x + (double)b.y * b.y + (double)b.z * b.z + (double)b.w * b.w;
        union { _Float16 h[8]; int4 v; } pk;
        pk.h[0] = (_Float16)(a.x * 1024.0f); pk.h[1] = (_Float16)(a.y * 1024.0f);
        pk.h[2] = (_Float16)(a.z * 1024.0f); pk.h[3] = (_Float16)(a.w * 1024.0f);
        pk.h[4] = (_Float16)(b.x * 1024.0f); pk.h[5] = (_Float16)(b.y * 1024.0f);
        pk.h[6] = (_Float16)(b.z * 1024.0f); pk.h[7] = (_Float16)(b.w * 1024.0f);
        *(int4*)(dst + i * 8) = pk.v;
    }
    esum[t] = s;
    __syncthreads();
    if (t < 64) {
        const int r2 = blockIdx.x * 64 + t;
        en2[r2] = (float)(esum[t * 4] + esum[t * 4 + 1] + esum[t * 4 + 2] + esum[t * 4 + 3]);
    }
}

// per-pixel squared norms (exactly round-1's kernel — known-passing numerics)
__global__ __launch_bounds__(256) void k_xn2(const float* __restrict__ x,
                                             float* __restrict__ xn2) {
    int n = blockIdx.x * 256 + threadIdx.x;
    int b = n >> 10, hw = n & 1023;
    const float* xp = x + b * 262144 + hw;
    double s = 0.0;
    for (int c = 0; c < 256; ++c) { double v = xp[c * 1024]; s += v * v; }
    xn2[n] = (float)s;
}

// ---------------------------------------------------------------------------
// Transpose x NCHW -> pixel-major fp16 [n][256]
__global__ __launch_bounds__(256) void k_prep(const float* __restrict__ x,
                                              ushort* __restrict__ xhi) {
    __shared__ float T[256 * 68];
    const int t = threadIdx.x, bid = blockIdx.x;
    const int b = bid >> 4, hw0 = (bid & 15) << 6;   // 64 contiguous pixels
    const float* xb = x + b * 262144 + hw0;
#pragma unroll
    for (int i = 0; i < 16; ++i) {
        const int jv = i * 256 + t, c = jv >> 4, p4 = (jv & 15) << 2;
        *(float4*)(&T[c * 68 + p4]) = *(const float4*)(xb + c * 1024 + p4);
    }
    __syncthreads();
    const int p = t >> 2, q = t & 3;
    ushort* orow = xhi + (size_t)(bid * 64 + p) * 256 + q * 64;
#pragma unroll
    for (int g = 0; g < 8; ++g) {
        union { _Float16 h[8]; int4 v; } pk;
#pragma unroll
        for (int j = 0; j < 8; ++j) pk.h[j] = (_Float16)T[(q * 64 + g * 8 + j) * 68 + p];
        *(int4*)(orow + g * 8) = pk.v;
    }
}

// ---------------------------------------------------------------------------
// fp16 MFMA sweep: approx dist' = 1024*en - 2*dot(x, 1024*e); per-pixel lex top-2.
// Block: 128 pixels x all 1024 codes (kt loop of 8 x 128). Wave tile 64x64.
__global__ __launch_bounds__(256) void k_sweep(const ushort* __restrict__ xhi,
                                               const ushort* __restrict__ ehi,
                                               const float* __restrict__ en2,
                                               int* __restrict__ idxv,
                                               int* __restrict__ rlist,
                                               unsigned* __restrict__ rcnt) {
    __shared__ ushort As[128 * 64];   // [p][d] chunk, xor-swizzled 16B groups
    __shared__ ushort Bs[128 * 64];   // [k][d] chunk, same swizzle
    __shared__ float  Ds[64 * 132];   // half-dump: [code-in-half][pixel]
    __shared__ float  enSs[128];
    __shared__ ull    ltop[256][2];
    __shared__ ull    top2a[128], top2b[128];

    const int t = threadIdx.x, bid = blockIdx.x;
    const int p0 = bid << 7;
    const int lane = t & 63, w = t >> 6, wm = w >> 1, wk = w & 1;
    const int quad = lane >> 4, l15 = lane & 15;

    if (t < 128) { top2a[t] = ~0ull; top2b[t] = ~0ull; }

    for (int kt = 0; kt < 8; ++kt) {
        if (t < 128) enSs[t] = en2[kt * 128 + t] * 1024.0f;
        const f4v zacc = {0.f, 0.f, 0.f, 0.f};
        f4v acc[4][4];
#pragma unroll
        for (int mi = 0; mi < 4; ++mi)
#pragma unroll
            for (int ni = 0; ni < 4; ++ni) acc[mi][ni] = zacc;

        for (int dc = 0; dc < 4; ++dc) {
            __syncthreads();
#pragma unroll
            for (int i = 0; i < 4; ++i) {
                const int jv = i * 256 + t, row = jv >> 3, g = jv & 7;
                const int pg = (g ^ ((row >> 1) & 7)) << 3;
                *(int4*)(&As[row * 64 + pg]) =
                    *(const int4*)(&xhi[(size_t)(p0 + row) * 256 + dc * 64 + g * 8]);
                *(int4*)(&Bs[row * 64 + pg]) =
                    *(const int4*)(&ehi[(size_t)(kt * 128 + row) * 256 + dc * 64 + g * 8]);
            }
            __syncthreads();
#pragma unroll
            for (int ks = 0; ks < 2; ++ks) {
                h8 av[4], bv[4];
#pragma unroll
                for (int mi = 0; mi < 4; ++mi) {
                    const int m = wm * 64 + mi * 16 + l15;
                    const int pg = ((4 * ks + quad) ^ ((m >> 1) & 7)) << 3;
                    av[mi] = *(h8*)(&As[m * 64 + pg]);
                    const int n = wk * 64 + mi * 16 + l15;
                    const int pgn = ((4 * ks + quad) ^ ((n >> 1) & 7)) << 3;
                    bv[mi] = *(h8*)(&Bs[n * 64 + pgn]);
                }
#pragma unroll
                for (int mi = 0; mi < 4; ++mi)
#pragma unroll
                    for (int ni = 0; ni < 4; ++ni)
                        acc[mi][ni] = __builtin_amdgcn_mfma_f32_16x16x32_f16(
                            av[mi], bv[ni], acc[mi][ni], 0, 0, 0);
            }
        }
        // epilogue: dump + scan each 64-code half
        for (int h = 0; h < 2; ++h) {
            __syncthreads();
            if (wk == h) {
#pragma unroll
                for (int mi = 0; mi < 4; ++mi)
#pragma unroll
                    for (int ni = 0; ni < 4; ++ni) {
                        const int np = ni * 16 + l15;
                        const int mb = wm * 64 + mi * 16 + quad * 4;
                        *(f4v*)(&Ds[np * 132 + mb]) = acc[mi][ni];
                    }
            }
            __syncthreads();
            {
                const int m = t & 127, nh = t >> 7;
                ull k1 = ~0ull, k2 = ~0ull;
#pragma unroll 4
                for (int j = 0; j < 32; ++j) {
                    const int np = nh * 32 + j;
                    const float D = fmaf(-2.0f, Ds[np * 132 + m], enSs[h * 64 + np]);
                    const ull key = ((ull)__float_as_uint(D) << 32) |
                                    (unsigned)(kt * 128 + h * 64 + np);
                    if (key < k1) { k2 = k1; k1 = key; }
                    else if (key < k2) k2 = key;
                }
                ltop[t][0] = k1; ltop[t][1] = k2;
            }
            __syncthreads();
            if (t < 128) {
                ull c1 = top2a[t], c2 = top2b[t];
#pragma unroll
                for (int s = 0; s < 2; ++s) {
                    const ull x1 = ltop[t + s * 128][0], x2 = ltop[t + s * 128][1];
                    if (x1 < c1) { c2 = c1; c1 = x1; } else if (x1 < c2) c2 = x1;
                    if (x2 < c1) { c2 = c1; c1 = x2; } else if (x2 < c2) c2 = x2;
                }
                top2a[t] = c1; top2b[t] = c2;
            }
        }
    }
    __syncthreads();
    if (t < 128) {
        const ull a = top2a[t], b2 = top2b[t];
        const int k1 = (int)(unsigned)(a & 0xffffffffu);
        const float D1 = __uint_as_float((unsigned)(a >> 32));
        const float D2 = __uint_as_float((unsigned)(b2 >> 32));
        const int P = p0 + t;
        idxv[P] = k1;
        const bool risky = (D2 - D1) <= SWEEP_W;
        const ull mask = __ballot(risky);
        const int ln = t & 63;
        const int pre = __popcll(mask & ((1ull << ln) - 1ull));
        unsigned base = 0;
        if (ln == 0) base = atomicAdd(rcnt, (unsigned)__popcll(mask));
        base = (unsigned)__shfl((int)base, 0, 64);
        if (risky) rlist[base + pre] = P;
    }
}

// ---------------------------------------------------------------------------
// Exact f32 rescan of risky pixels (replicates round-1's validated numerics).
// Unit = (tile of 64 listed pixels) x (kt of 128 codes); u64 atomicMin resolves.
__global__ __launch_bounds__(256) void k_rescan(const float* __restrict__ x,
                                                const float* __restrict__ cb,
                                                const float* __restrict__ en2,
                                                const float* __restrict__ xn2,
                                                const int* __restrict__ rlist,
                                                const unsigned* __restrict__ rcnt,
                                                ull* __restrict__ rkey) {
    __shared__ float xs[64 * 68];
    __shared__ float es[64 * 132];
    __shared__ int plist[64];
    const int t = threadIdx.x;
    const unsigned cnt = *rcnt;
    const int nunits = (int)(((cnt + 63) >> 6) << 3);
    const int ti = t >> 4, tj = t & 15;

    for (int u = blockIdx.x; u < nunits; u += gridDim.x) {
        const int tile = u >> 3, kt = u & 7;
        __syncthreads();
        if (t < 64) {
            const int li = tile * 64 + t;
            plist[t] = rlist[li < (int)cnt ? li : 0];
        }
        __syncthreads();

        float xnr[4]; int pid[4];
#pragma unroll
        for (int r = 0; r < 4; ++r) {
            pid[r] = plist[ti * 4 + r];
            xnr[r] = xn2[pid[r]];
        }
        float acc[4][8];
#pragma unroll
        for (int r = 0; r < 4; ++r)
#pragma unroll
            for (int j = 0; j < 8; ++j) acc[r][j] = 0.f;
        float best_s[4]; int best_k[4];
#pragma unroll
        for (int r = 0; r < 4; ++r) { best_s[r] = INFINITY; best_k[r] = 0; }

        for (int dc = 0; dc < 4; ++dc) {
            __syncthreads();
            {   // stage xs (scattered pixel columns, L2/L3-hot)
                const int p = t & 63, coff = t >> 6;
                const int P = plist[p];
                const float* xp = x + ((P >> 10) * 262144 + (P & 1023));
#pragma unroll
                for (int cc = 0; cc < 16; ++cc) {
                    const int cl = coff * 16 + cc;
                    xs[cl * 68 + p] = xp[(dc * 64 + cl) * 1024];
                }
            }
#pragma unroll
            for (int i = 0; i < 8; ++i) {
                const int jv = i * 256 + t, k = jv >> 4, d4 = (jv & 15) << 2;
                const float4 v = *(const float4*)(cb + (size_t)(kt * 128 + k) * 256 + dc * 64 + d4);
                es[(d4 + 0) * 132 + k] = v.x; es[(d4 + 1) * 132 + k] = v.y;
                es[(d4 + 2) * 132 + k] = v.z; es[(d4 + 3) * 132 + k] = v.w;
            }
            __syncthreads();
#pragma unroll 4
            for (int d = 0; d < 64; ++d) {
                const float4 xv = *(const float4*)(&xs[d * 68 + ti * 4]);
                const float4 e0 = *(const float4*)(&es[d * 132 + tj * 8]);
                const float4 e1 = *(const float4*)(&es[d * 132 + tj * 8 + 4]);
                const float xr[4] = {xv.x, xv.y, xv.z, xv.w};
                const float ej[8] = {e0.x, e0.y, e0.z, e0.w, e1.x, e1.y, e1.z, e1.w};
#pragma unroll
                for (int r = 0; r < 4; ++r)
#pragma unroll
                    for (int j = 0; j < 8; ++j)
                        acc[r][j] = fmaf(xr[r], ej[j], acc[r][j]);
            }
        }
#pragma unroll
        for (int j = 0; j < 8; ++j) {
            const int k = kt * 128 + tj * 8 + j;
            const float en = en2[k];
#pragma unroll
            for (int r = 0; r < 4; ++r) {
                const float s1 = xnr[r] + en;
                const float dist = fmaf(-2.f, acc[r][j], s1);
                if (dist < best_s[r] || (dist == best_s[r] && k < best_k[r])) {
                    best_s[r] = dist; best_k[r] = k;
                }
            }
        }
#pragma unroll
        for (int r = 0; r < 4; ++r) {
            float s = best_s[r]; int k = best_k[r];
            for (int m = 1; m < 16; m <<= 1) {
                const float s2 = __shfl_xor(s, m, 64);
                const int k2 = __shfl_xor(k, m, 64);
                if (s2 < s || (s2 == s && k2 < k)) { s = s2; k = k2; }
            }
            if (tj == 0 && (tile * 64 + ti * 4 + r) < (int)cnt) {
                const ull key = ((ull)__float_as_uint(s) << 32) | (unsigned)k;
                atomicMin(&rkey[pid[r]], key);
            }
        }
    }
}

__global__ __launch_bounds__(256) void k_resolve(const ull* __restrict__ rkey,
                                                 int* __restrict__ idxv) {
    const int n = blockIdx.x * 256 + threadIdx.x;
    const ull k = rkey[n];
    if (k != ~0ull) idxv[n] = (int)(unsigned)(k & 0xffffffffu);
}

// ---------------------------------------------------------------------------
// Gather codebook rows -> q_out + (q-x)^2 sum + histogram + idx_f (round-1 + adds)
__global__ __launch_bounds__(256) void k_gather(const float* __restrict__ x,
                                                const float* __restrict__ cb,
                                                const int* __restrict__ idxv,
                                                float* __restrict__ out,
                                                double* __restrict__ sumsq,
                                                unsigned* __restrict__ counts) {
    __shared__ __align__(16) float cs[32 * 260];
    __shared__ int   kidx[32];
    __shared__ float wpart[4];

    const int t = threadIdx.x, bid = blockIdx.x;
    const int n0 = bid * 32;
    if (t < 32) {
        const int kk = idxv[n0 + t];
        kidx[t] = kk;
        atomicAdd(&counts[kk], 1u);
        out[IDX_OFF + n0 + t] = (float)kk;
    }
    __syncthreads();
#pragma unroll
    for (int i = 0; i < 8; ++i) {
        int jv = (i << 8) + t;
        int p = jv >> 6, c4 = (jv & 63) << 2;
        const float4 v = *(const float4*)(cb + (size_t)kidx[p] * 256 + c4);
        *(float4*)(&cs[p * 260 + c4]) = v;
    }
    __syncthreads();

    const int b = bid >> 5, h = bid & 31;
    const float* xb = x + b * 262144 + h * 32;
    float* qb = out + Q_OFF + b * 262144 + h * 32;

    float local = 0.f;
#pragma unroll
    for (int i = 0; i < 8; ++i) {
        int j = (i << 8) + t;
        int c = j >> 3, w4 = (j & 7) << 2;
        const float q0 = cs[(w4 + 0) * 260 + c];
        const float q1 = cs[(w4 + 1) * 260 + c];
        const float q2 = cs[(w4 + 2) * 260 + c];
        const float q3 = cs[(w4 + 3) * 260 + c];
        const float4 xv = *(const float4*)(xb + c * 1024 + w4);
        const float d0 = q0 - xv.x, d1 = q1 - xv.y;
        const float d2 = q2 - xv.z, d3 = q3 - xv.w;
        local += d0 * d0 + d1 * d1 + d2 * d2 + d3 * d3;
        qb[c * 1024 + w4 + 0] = q0;
        qb[c * 1024 + w4 + 1] = q1;
        qb[c * 1024 + w4 + 2] = q2;
        qb[c * 1024 + w4 + 3] = q3;
    }
    for (int m = 32; m > 0; m >>= 1) local += __shfl_down(local, m, 64);
    if ((t & 63) == 0) wpart[t >> 6] = local;
    __syncthreads();
    if (t == 0) {
        const float bs = wpart[0] + wpart[1] + wpart[2] + wpart[3];
        atomicAdd(sumsq, (double)bs);
    }
}

__global__ __launch_bounds__(256) void k_final(const unsigned* __restrict__ counts,
                                               const double* __restrict__ sumsq,
                                               float* __restrict__ out) {
    __shared__ double part[256];
    const int t = threadIdx.x;
    double s = 0.0;
    for (int k = t; k < K_; k += 256) {
        const double p = (double)counts[k] / (double)N_;
        s += p * log(p + 1e-10);
    }
    part[t] = s;
    __syncthreads();
    for (int off = 128; off > 0; off >>= 1) {
        if (t < off) part[t] += part[t + off];
        __syncthreads();
    }
    if (t == 0) {
        out[PERP_OFF] = (float)exp(-part[0]);
        out[0] = (float)(sumsq[0] * 1.25 / (double)NELEM);
    }
}

// ---------------------------------------------------------------------------
extern "C" void kernel_launch(void* const* d_in, const int* in_sizes, int n_in,
                              void* d_out, int out_size, void* d_ws, size_t ws_size,
                              hipStream_t stream) {
    const float* x  = (const float*)d_in[0];
    const float* cb = (const float*)d_in[1];
    float* out = (float*)d_out;
    char*  ws  = (char*)d_ws;

    unsigned* counts = (unsigned*)(ws + WS_COUNTS);
    double*   sumsq  = (double*)(ws + WS_SUMSQ);
    unsigned* rcnt   = (unsigned*)(ws + WS_RISKCNT);
    float*    en2    = (float*)(ws + WS_EN2);
    float*    xn2    = (float*)(ws + WS_XN2);
    int*      idxv   = (int*)(ws + WS_IDX);
    int*      rlist  = (int*)(ws + WS_RLIST);
    ull*      rkey   = (ull*)(ws + WS_RKEY);
    ushort*   ehi    = (ushort*)(ws + WS_EHI);
    ushort*   xhi    = (ushort*)(ws + WS_XHI);

    hipMemsetAsync(ws, 0, 4168, stream);                       // counts+sumsq+rcnt
    hipMemsetAsync(ws + WS_RKEY, 0xFF, 32768 * 8, stream);     // rkey = +inf

    k_ecvt<<<16, 256, 0, stream>>>(cb, ehi, en2);
    k_xn2<<<128, 256, 0, stream>>>(x, xn2);
    k_prep<<<512, 256, 0, stream>>>(x, xhi);
    k_sweep<<<256, 256, 0, stream>>>(xhi, ehi, en2, idxv, rlist, rcnt);
    k_rescan<<<512, 256, 0, stream>>>(x, cb, en2, xn2, rlist, rcnt, rkey);
    k_resolve<<<128, 256, 0, stream>>>(rkey, idxv);
    k_gather<<<1024, 256, 0, stream>>>(x, cb, idxv, out, sumsq, counts);
    k_final<<<1, 256, 0, stream>>>(counts, sumsq, out);
}

// Round 3
// 285.728 us; speedup vs baseline: 1.9183x; 1.9183x over previous
//
#include <hip/hip_runtime.h>
#include <math.h>

// Problem constants
#define K_    1024
#define N_    32768
#define NELEM 8388608

// d_out layout (floats, reference return order)
#define Q_OFF    1
#define PERP_OFF 8388609
#define IDX_OFF  8388610

// d_out Q-region scratch (overwritten by k_gather at the end; 16B-aligned bases)
#define XLO_F_OFF 4          // xlo: 32768*256 fp16 = 8.39M halfwords = 4,194,304 floats
#define ELO_F_OFF 4194308    // elo: 1024*256 fp16 = 262,144 halfwords = 131,072 floats

typedef unsigned long long ull;
typedef _Float16 h8  __attribute__((ext_vector_type(8)));
typedef float    f4v __attribute__((ext_vector_type(4)));

// ws layout (bytes) — identical footprint to round-2 (known to fit)
#define WS_COUNTS  0        // 1024 u32
#define WS_SUMSQ   4096     // double
#define WS_RISKCNT 4104     // u32
#define WS_EN2     4160     // 1024 f32
#define WS_XN2     8256     // 32768 f32
#define WS_IDX     139328   // 32768 i32
#define WS_RLIST   270400   // 32768 i32
#define WS_RKEY    401472   // 32768 u64
#define WS_EHI     663616   // 1024*256 fp16
#define WS_XHI     1187904  // 32768*256 fp16 (pixel-major)

// risky-gap threshold (scaled-by-1024 domain). Rigorous bound ~0.075
// (2*(ref ULP(256) rounding 0.033 + split-fp16 residual 0.003)); 2x margin.
#define SWEEP_W 0.15f

__device__ __forceinline__ unsigned ordfix(unsigned u) {
    // monotone float-bits -> uint (handles negatives)
    return u ^ ((u & 0x80000000u) ? 0xFFFFFFFFu : 0x80000000u);
}
__device__ __forceinline__ unsigned ordunfix(unsigned u) {
    return (u & 0x80000000u) ? (u ^ 0x80000000u) : ~u;
}

// ---------------------------------------------------------------------------
// Codebook -> ehi = fp16(1024 e), elo = fp16((1024e - ehi)*2048), en2 (f64->f32)
__global__ __launch_bounds__(256) void k_ecvt(const float* __restrict__ cb,
                                              ushort* __restrict__ ehi,
                                              ushort* __restrict__ elo,
                                              float* __restrict__ en2) {
    __shared__ double esum[256];
    const int t = threadIdx.x;
    const int row = blockIdx.x * 64 + (t >> 2);
    const int seg = t & 3;
    const float* src = cb + (size_t)row * 256 + seg * 64;
    ushort* dh = ehi + (size_t)row * 256 + seg * 64;
    ushort* dl = elo + (size_t)row * 256 + seg * 64;
    double s = 0.0;
#pragma unroll
    for (int i = 0; i < 8; ++i) {
        const float4 a = *(const float4*)(src + i * 8);
        const float4 b = *(const float4*)(src + i * 8 + 4);
        s += (double)a.x * a.x + (double)a.y * a.y + (double)a.z * a.z + (double)a.w * a.w;
        s += (double)b.x * b.x + (double)b.y * b.y + (double)b.z * b.z + (double)b.w * b.w;
        float v[8] = {a.x, a.y, a.z, a.w, b.x, b.y, b.z, b.w};
        union { _Float16 h[8]; int4 q; } ph, pl;
#pragma unroll
        for (int j = 0; j < 8; ++j) {
            const float es = v[j] * 1024.0f;            // exact (pow2)
            const _Float16 hi = (_Float16)es;
            ph.h[j] = hi;
            pl.h[j] = (_Float16)((es - (float)hi) * 2048.0f); // Sterbenz-exact diff
        }
        *(int4*)(dh + i * 8) = ph.q;
        *(int4*)(dl + i * 8) = pl.q;
    }
    esum[t] = s;
    __syncthreads();
    if (t < 64) {
        const int r2 = blockIdx.x * 64 + t;
        en2[r2] = (float)(esum[t * 4] + esum[t * 4 + 1] + esum[t * 4 + 2] + esum[t * 4 + 3]);
    }
}

// ---------------------------------------------------------------------------
// x NCHW -> pixel-major xhi/xlo fp16 + per-pixel xn2 (fused)
__global__ __launch_bounds__(256) void k_prep(const float* __restrict__ x,
                                              ushort* __restrict__ xhi,
                                              ushort* __restrict__ xlo,
                                              float* __restrict__ xn2) {
    __shared__ float T[256 * 68];
    __shared__ double xpart[256];
    const int t = threadIdx.x, bid = blockIdx.x;
    const int b = bid >> 4, hw0 = (bid & 15) << 6;   // 64 contiguous pixels
    const float* xb = x + b * 262144 + hw0;
#pragma unroll
    for (int i = 0; i < 16; ++i) {
        const int jv = i * 256 + t, c = jv >> 4, p4 = (jv & 15) << 2;
        *(float4*)(&T[c * 68 + p4]) = *(const float4*)(xb + c * 1024 + p4);
    }
    __syncthreads();
    const int p = t >> 2, q = t & 3;
    ushort* oh = xhi + (size_t)(bid * 64 + p) * 256 + q * 64;
    ushort* ol = xlo + (size_t)(bid * 64 + p) * 256 + q * 64;
    double sn = 0.0;
#pragma unroll
    for (int g = 0; g < 8; ++g) {
        union { _Float16 h[8]; int4 v; } ph, pl;
#pragma unroll
        for (int j = 0; j < 8; ++j) {
            const float v = T[(q * 64 + g * 8 + j) * 68 + p];
            sn += (double)v * v;
            const _Float16 hi = (_Float16)v;
            ph.h[j] = hi;
            pl.h[j] = (_Float16)((v - (float)hi) * 2048.0f);
        }
        *(int4*)(oh + g * 8) = ph.v;
        *(int4*)(ol + g * 8) = pl.v;
    }
    xpart[t] = sn;
    __syncthreads();
    if (t < 64)
        xn2[bid * 64 + t] = (float)(xpart[t * 4] + xpart[t * 4 + 1] +
                                    xpart[t * 4 + 2] + xpart[t * 4 + 3]);
}

// ---------------------------------------------------------------------------
// Split-fp16 MFMA sweep. Block = 64 pixels x 1024 codes (kt loop: 4 x 256).
// 4 waves; wave w covers 64 px x 64 codes per kt. A via swizzled LDS;
// B-fragments loaded directly from L2-resident ehi/elo.
// D_s = 1024*en - 2*(acc1 + acc2/2048); sign-corrected lex top-2 per pixel.
__global__ __launch_bounds__(256, 2) void k_sweep(const ushort* __restrict__ xhi,
                                                  const ushort* __restrict__ xlo,
                                                  const ushort* __restrict__ ehi,
                                                  const ushort* __restrict__ elo,
                                                  const float* __restrict__ en2,
                                                  int* __restrict__ idxv,
                                                  int* __restrict__ rlist,
                                                  unsigned* __restrict__ rcnt) {
    __shared__ ushort Ah[64 * 32], Al[64 * 32];   // 4 KB each, per-dc chunk
    __shared__ float  Ds[128 * 64];               // 32 KB half-dump (xor-swizzled px)
    __shared__ float  enSs[256];
    __shared__ ull    ltop[256][2];
    __shared__ ull    top2a[64], top2b[64];

    const int t = threadIdx.x, bid = blockIdx.x;
    const int p0 = bid << 6;
    const int w = t >> 6, lane = t & 63;
    const int quad = lane >> 4, l15 = lane & 15;

    if (t < 64) { top2a[t] = ~0ull; top2b[t] = ~0ull; }

    for (int kt = 0; kt < 4; ++kt) {
        enSs[t] = en2[kt * 256 + t] * 1024.0f;
        const f4v z = {0.f, 0.f, 0.f, 0.f};
        f4v acc1[4][4], acc2[4][4];
#pragma unroll
        for (int mi = 0; mi < 4; ++mi)
#pragma unroll
            for (int ni = 0; ni < 4; ++ni) { acc1[mi][ni] = z; acc2[mi][ni] = z; }

        for (int dc = 0; dc < 8; ++dc) {
            // B-fragments straight from global (L2-hot; issued early)
            h8 bh[4], bl[4];
#pragma unroll
            for (int ni = 0; ni < 4; ++ni) {
                const size_t n = (size_t)(kt * 256 + w * 64 + ni * 16 + l15);
                bh[ni] = *(const h8*)(ehi + n * 256 + dc * 32 + quad * 8);
                bl[ni] = *(const h8*)(elo + n * 256 + dc * 32 + quad * 8);
            }
            __syncthreads();   // Ah/Al reuse guard (also flushes enSs on dc==0)
            {
                const int r = t >> 2, s = t & 3;
                const int g = ((s ^ ((r >> 1) & 3)) << 3);
                *(int4*)(&Ah[r * 32 + g]) =
                    *(const int4*)(xhi + (size_t)(p0 + r) * 256 + dc * 32 + s * 8);
                *(int4*)(&Al[r * 32 + g]) =
                    *(const int4*)(xlo + (size_t)(p0 + r) * 256 + dc * 32 + s * 8);
            }
            __syncthreads();
            h8 ah[4], al[4];
#pragma unroll
            for (int mi = 0; mi < 4; ++mi) {
                const int m = mi * 16 + l15;
                const int g = ((quad ^ ((m >> 1) & 3)) << 3);
                ah[mi] = *(const h8*)(&Ah[m * 32 + g]);
                al[mi] = *(const h8*)(&Al[m * 32 + g]);
            }
#pragma unroll
            for (int mi = 0; mi < 4; ++mi)
#pragma unroll
                for (int ni = 0; ni < 4; ++ni) {
                    acc1[mi][ni] = __builtin_amdgcn_mfma_f32_16x16x32_f16(
                        ah[mi], bh[ni], acc1[mi][ni], 0, 0, 0);
                    acc2[mi][ni] = __builtin_amdgcn_mfma_f32_16x16x32_f16(
                        ah[mi], bl[ni], acc2[mi][ni], 0, 0, 0);
                    acc2[mi][ni] = __builtin_amdgcn_mfma_f32_16x16x32_f16(
                        al[mi], bh[ni], acc2[mi][ni], 0, 0, 0);
                }
        }
        // epilogue: two 128-code halves
#pragma unroll
        for (int h = 0; h < 2; ++h) {
            __syncthreads();
            if ((w >> 1) == h) {
                const int wl = w & 1;
#pragma unroll
                for (int mi = 0; mi < 4; ++mi)
#pragma unroll
                    for (int ni = 0; ni < 4; ++ni) {
                        const f4v cmb = acc1[mi][ni] + acc2[mi][ni] * (1.0f / 2048.0f);
                        const int np = wl * 64 + ni * 16 + l15;
                        const int mb = mi * 16 + quad * 4;
                        const int grp = (mb >> 2) ^ (np & 15);
                        *(f4v*)(&Ds[np * 64 + grp * 4]) = cmb;
                    }
            }
            __syncthreads();
            {
                const int p = t & 63, cb0 = (t >> 6) * 32;
                ull k1 = ~0ull, k2 = ~0ull;
#pragma unroll 4
                for (int j = 0; j < 32; ++j) {
                    const int c = cb0 + j;
                    const int addr = c * 64 + ((((p >> 2) ^ (c & 15)) << 2) | (p & 3));
                    const float D = fmaf(-2.0f, Ds[addr], enSs[h * 128 + c]);
                    const ull key = ((ull)ordfix(__float_as_uint(D)) << 32) |
                                    (unsigned)(kt * 256 + h * 128 + c);
                    if (key < k1) { k2 = k1; k1 = key; }
                    else if (key < k2) k2 = key;
                }
                ltop[t][0] = k1; ltop[t][1] = k2;
            }
            __syncthreads();
            if (t < 64) {
                ull c1 = top2a[t], c2 = top2b[t];
#pragma unroll
                for (int s = 0; s < 4; ++s) {
                    const ull x1 = ltop[t + s * 64][0], x2 = ltop[t + s * 64][1];
                    if (x1 < c1) { c2 = c1; c1 = x1; } else if (x1 < c2) c2 = x1;
                    if (x2 < c1) { c2 = c1; c1 = x2; } else if (x2 < c2) c2 = x2;
                }
                top2a[t] = c1; top2b[t] = c2;
            }
            __syncthreads();
        }
    }
    if (t < 64) {
        const ull a = top2a[t], b2 = top2b[t];
        const int k1 = (int)(unsigned)(a & 0xffffffffu);
        const float D1 = __uint_as_float(ordunfix((unsigned)(a >> 32)));
        const float D2 = __uint_as_float(ordunfix((unsigned)(b2 >> 32)));
        const int P = p0 + t;
        idxv[P] = k1;
        const bool risky = (D2 - D1) <= SWEEP_W;
        const ull mask = __ballot(risky);
        const int pre = __popcll(mask & ((1ull << t) - 1ull));
        unsigned base = 0;
        if (t == 0) base = atomicAdd(rcnt, (unsigned)__popcll(mask));
        base = (unsigned)__shfl((int)base, 0, 64);
        if (risky) rlist[base + pre] = P;
    }
}

// ---------------------------------------------------------------------------
// Exact f32 rescan of risky pixels (validated in rounds 1-2: replicates np ref).
__global__ __launch_bounds__(256) void k_rescan(const float* __restrict__ x,
                                                const float* __restrict__ cb,
                                                const float* __restrict__ en2,
                                                const float* __restrict__ xn2,
                                                const int* __restrict__ rlist,
                                                const unsigned* __restrict__ rcnt,
                                                ull* __restrict__ rkey) {
    __shared__ float xs[64 * 68];
    __shared__ float es[64 * 132];
    __shared__ int plist[64];
    const int t = threadIdx.x;
    const unsigned cnt = *rcnt;
    const int nunits = (int)(((cnt + 63) >> 6) << 3);
    const int ti = t >> 4, tj = t & 15;

    for (int u = blockIdx.x; u < nunits; u += gridDim.x) {
        const int tile = u >> 3, kt = u & 7;
        __syncthreads();
        if (t < 64) {
            const int li = tile * 64 + t;
            plist[t] = rlist[li < (int)cnt ? li : 0];
        }
        __syncthreads();

        float xnr[4]; int pid[4];
#pragma unroll
        for (int r = 0; r < 4; ++r) {
            pid[r] = plist[ti * 4 + r];
            xnr[r] = xn2[pid[r]];
        }
        float acc[4][8];
#pragma unroll
        for (int r = 0; r < 4; ++r)
#pragma unroll
            for (int j = 0; j < 8; ++j) acc[r][j] = 0.f;
        float best_s[4]; int best_k[4];
#pragma unroll
        for (int r = 0; r < 4; ++r) { best_s[r] = INFINITY; best_k[r] = 0; }

        for (int dc = 0; dc < 4; ++dc) {
            __syncthreads();
            {
                const int p = t & 63, coff = t >> 6;
                const int P = plist[p];
                const float* xp = x + ((P >> 10) * 262144 + (P & 1023));
#pragma unroll
                for (int cc = 0; cc < 16; ++cc) {
                    const int cl = coff * 16 + cc;
                    xs[cl * 68 + p] = xp[(dc * 64 + cl) * 1024];
                }
            }
#pragma unroll
            for (int i = 0; i < 8; ++i) {
                const int jv = i * 256 + t, k = jv >> 4, d4 = (jv & 15) << 2;
                const float4 v = *(const float4*)(cb + (size_t)(kt * 128 + k) * 256 + dc * 64 + d4);
                es[(d4 + 0) * 132 + k] = v.x; es[(d4 + 1) * 132 + k] = v.y;
                es[(d4 + 2) * 132 + k] = v.z; es[(d4 + 3) * 132 + k] = v.w;
            }
            __syncthreads();
#pragma unroll 4
            for (int d = 0; d < 64; ++d) {
                const float4 xv = *(const float4*)(&xs[d * 68 + ti * 4]);
                const float4 e0 = *(const float4*)(&es[d * 132 + tj * 8]);
                const float4 e1 = *(const float4*)(&es[d * 132 + tj * 8 + 4]);
                const float xr[4] = {xv.x, xv.y, xv.z, xv.w};
                const float ej[8] = {e0.x, e0.y, e0.z, e0.w, e1.x, e1.y, e1.z, e1.w};
#pragma unroll
                for (int r = 0; r < 4; ++r)
#pragma unroll
                    for (int j = 0; j < 8; ++j)
                        acc[r][j] = fmaf(xr[r], ej[j], acc[r][j]);
            }
        }
#pragma unroll
        for (int j = 0; j < 8; ++j) {
            const int k = kt * 128 + tj * 8 + j;
            const float en = en2[k];
#pragma unroll
            for (int r = 0; r < 4; ++r) {
                const float s1 = xnr[r] + en;
                const float dist = fmaf(-2.f, acc[r][j], s1);
                if (dist < best_s[r] || (dist == best_s[r] && k < best_k[r])) {
                    best_s[r] = dist; best_k[r] = k;
                }
            }
        }
#pragma unroll
        for (int r = 0; r < 4; ++r) {
            float s = best_s[r]; int k = best_k[r];
            for (int m = 1; m < 16; m <<= 1) {
                const float s2 = __shfl_xor(s, m, 64);
                const int k2 = __shfl_xor(k, m, 64);
                if (s2 < s || (s2 == s && k2 < k)) { s = s2; k = k2; }
            }
            if (tj == 0 && (tile * 64 + ti * 4 + r) < (int)cnt) {
                // dist includes xn (~256) -> strictly positive, raw-bit lex is safe
                const ull key = ((ull)__float_as_uint(s) << 32) | (unsigned)k;
                atomicMin(&rkey[pid[r]], key);
            }
        }
    }
}

__global__ __launch_bounds__(256) void k_resolve(const ull* __restrict__ rkey,
                                                 int* __restrict__ idxv) {
    const int n = blockIdx.x * 256 + threadIdx.x;
    const ull k = rkey[n];
    if (k != ~0ull) idxv[n] = (int)(unsigned)(k & 0xffffffffu);
}

// ---------------------------------------------------------------------------
// Gather codebook rows -> q_out + (q-x)^2 sum + histogram + idx_f
__global__ __launch_bounds__(256) void k_gather(const float* __restrict__ x,
                                                const float* __restrict__ cb,
                                                const int* __restrict__ idxv,
                                                float* __restrict__ out,
                                                double* __restrict__ sumsq,
                                                unsigned* __restrict__ counts) {
    __shared__ __align__(16) float cs[32 * 260];
    __shared__ int   kidx[32];
    __shared__ float wpart[4];

    const int t = threadIdx.x, bid = blockIdx.x;
    const int n0 = bid * 32;
    if (t < 32) {
        const int kk = idxv[n0 + t];
        kidx[t] = kk;
        atomicAdd(&counts[kk], 1u);
        out[IDX_OFF + n0 + t] = (float)kk;
    }
    __syncthreads();
#pragma unroll
    for (int i = 0; i < 8; ++i) {
        int jv = (i << 8) + t;
        int p = jv >> 6, c4 = (jv & 63) << 2;
        const float4 v = *(const float4*)(cb + (size_t)kidx[p] * 256 + c4);
        *(float4*)(&cs[p * 260 + c4]) = v;
    }
    __syncthreads();

    const int b = bid >> 5, h = bid & 31;
    const float* xb = x + b * 262144 + h * 32;
    float* qb = out + Q_OFF + b * 262144 + h * 32;

    float local = 0.f;
#pragma unroll
    for (int i = 0; i < 8; ++i) {
        int j = (i << 8) + t;
        int c = j >> 3, w4 = (j & 7) << 2;
        const float q0 = cs[(w4 + 0) * 260 + c];
        const float q1 = cs[(w4 + 1) * 260 + c];
        const float q2 = cs[(w4 + 2) * 260 + c];
        const float q3 = cs[(w4 + 3) * 260 + c];
        const float4 xv = *(const float4*)(xb + c * 1024 + w4);
        const float d0 = q0 - xv.x, d1 = q1 - xv.y;
        const float d2 = q2 - xv.z, d3 = q3 - xv.w;
        local += d0 * d0 + d1 * d1 + d2 * d2 + d3 * d3;
        qb[c * 1024 + w4 + 0] = q0;
        qb[c * 1024 + w4 + 1] = q1;
        qb[c * 1024 + w4 + 2] = q2;
        qb[c * 1024 + w4 + 3] = q3;
    }
    for (int m = 32; m > 0; m >>= 1) local += __shfl_down(local, m, 64);
    if ((t & 63) == 0) wpart[t >> 6] = local;
    __syncthreads();
    if (t == 0) {
        const float bs = wpart[0] + wpart[1] + wpart[2] + wpart[3];
        atomicAdd(sumsq, (double)bs);
    }
}

__global__ __launch_bounds__(256) void k_final(const unsigned* __restrict__ counts,
                                               const double* __restrict__ sumsq,
                                               float* __restrict__ out) {
    __shared__ double part[256];
    const int t = threadIdx.x;
    double s = 0.0;
    for (int k = t; k < K_; k += 256) {
        const double p = (double)counts[k] / (double)N_;
        s += p * log(p + 1e-10);
    }
    part[t] = s;
    __syncthreads();
    for (int off = 128; off > 0; off >>= 1) {
        if (t < off) part[t] += part[t + off];
        __syncthreads();
    }
    if (t == 0) {
        out[PERP_OFF] = (float)exp(-part[0]);
        out[0] = (float)(sumsq[0] * 1.25 / (double)NELEM);
    }
}

// ---------------------------------------------------------------------------
extern "C" void kernel_launch(void* const* d_in, const int* in_sizes, int n_in,
                              void* d_out, int out_size, void* d_ws, size_t ws_size,
                              hipStream_t stream) {
    const float* x  = (const float*)d_in[0];
    const float* cb = (const float*)d_in[1];
    float* out = (float*)d_out;
    char*  ws  = (char*)d_ws;

    unsigned* counts = (unsigned*)(ws + WS_COUNTS);
    double*   sumsq  = (double*)(ws + WS_SUMSQ);
    unsigned* rcnt   = (unsigned*)(ws + WS_RISKCNT);
    float*    en2    = (float*)(ws + WS_EN2);
    float*    xn2    = (float*)(ws + WS_XN2);
    int*      idxv   = (int*)(ws + WS_IDX);
    int*      rlist  = (int*)(ws + WS_RLIST);
    ull*      rkey   = (ull*)(ws + WS_RKEY);
    ushort*   ehi    = (ushort*)(ws + WS_EHI);
    ushort*   xhi    = (ushort*)(ws + WS_XHI);
    // lo-parts live in the d_out Q region (scratch until k_gather overwrites it)
    ushort*   xlo    = (ushort*)(out + XLO_F_OFF);
    ushort*   elo    = (ushort*)(out + ELO_F_OFF);

    hipMemsetAsync(ws, 0, 4168, stream);                       // counts+sumsq+rcnt
    hipMemsetAsync(ws + WS_RKEY, 0xFF, 32768 * 8, stream);     // rkey = +inf

    k_ecvt<<<16, 256, 0, stream>>>(cb, ehi, elo, en2);
    k_prep<<<512, 256, 0, stream>>>(x, xhi, xlo, xn2);
    k_sweep<<<512, 256, 0, stream>>>(xhi, xlo, ehi, elo, en2, idxv, rlist, rcnt);
    k_rescan<<<512, 256, 0, stream>>>(x, cb, en2, xn2, rlist, rcnt, rkey);
    k_resolve<<<128, 256, 0, stream>>>(rkey, idxv);
    k_gather<<<1024, 256, 0, stream>>>(x, cb, idxv, out, sumsq, counts);
    k_final<<<1, 256, 0, stream>>>(counts, sumsq, out);
}